// Round 10
// baseline (611.981 us; speedup 1.0000x reference)
//
#include <hip/hip_runtime.h>
#include <hip/hip_bf16.h>
#include <cstdint>
#include <cstring>

typedef __bf16 bf16_t;
typedef __attribute__((ext_vector_type(8))) __bf16 bf16x8;
typedef __attribute__((ext_vector_type(4))) __bf16 bf16x4;
typedef __attribute__((ext_vector_type(4))) float f32x4;

#define B_ 8
#define T_ 2048
#define D_ 2048
#define M_ (B_ * T_)   // 16384
#define N2_ (2 * D_)   // 4096 (interleaved z/h columns)
#define K_ D_          // 2048
#define NT (K_ / 64)   // 32 K-tiles of BK=64

#define NC 32
#define CHUNK (T_ / NC)  // 64

#define BAR() __builtin_amdgcn_s_barrier()
#define WAIT_LGKM0() asm volatile("s_waitcnt lgkmcnt(0)" ::: "memory")
#define WAIT_VM(n) asm volatile("s_waitcnt vmcnt(" #n ")" ::: "memory")

__device__ __forceinline__ float bfbits_to_f(uint32_t u16) {
    uint32_t u = u16 << 16;
    float f;
    memcpy(&f, &u, 4);
    return f;
}

// ---------------- conversion kernels ----------------

__global__ void conv_x_kernel(const float4* __restrict__ in, bf16x4* __restrict__ out, int n4) {
    int i = blockIdx.x * blockDim.x + threadIdx.x;
    if (i >= n4) return;
    float4 v = in[i];
    bf16x4 o = { (bf16_t)v.x, (bf16_t)v.y, (bf16_t)v.z, (bf16_t)v.w };
    out[i] = o;
}

// Pack Wz/Wh interleaved by row: Wb[2e] = Wz[e], Wb[2e+1] = Wh[e]
__global__ void conv_w_kernel(const float4* __restrict__ Wz, const float4* __restrict__ Wh,
                              bf16x4* __restrict__ Wb, int n4, int d4) {
    int i = blockIdx.x * blockDim.x + threadIdx.x;
    if (i >= n4) return;
    int row = i / d4;
    int c = i - row * d4;
    float4 vz = Wz[i];
    float4 vh = Wh[i];
    bf16x4 oz = { (bf16_t)vz.x, (bf16_t)vz.y, (bf16_t)vz.z, (bf16_t)vz.w };
    bf16x4 oh = { (bf16_t)vh.x, (bf16_t)vh.y, (bf16_t)vh.z, (bf16_t)vh.w };
    Wb[(size_t)(2 * row) * d4 + c] = oz;
    Wb[(size_t)(2 * row + 1) * d4 + c] = oh;
}

// ---------------- GEMM (256x256, BK=64, 8-phase, swizzled LDS) ----------------

__device__ __forceinline__ void gload_lds16(const bf16_t* g, char* l) {
    __builtin_amdgcn_global_load_lds(
        (__attribute__((address_space(1))) void*)(g),
        (__attribute__((address_space(3))) void*)(l), 16, 0, 0);
}

// LDS map (per buffer p in {0,1}):  A at p*65536, B at p*65536+32768.
// Logical tile [256 rows][64 k] bf16, row stride 128B; within a row, 16B chunk
// c stored at chunk slot c ^ (row & 7)  (T2 XOR swizzle, bank-conflict-free).
// global_load_lds writes linearly; the global SOURCE address is pre-inverse-swizzled.

__global__ __launch_bounds__(512, 2) void gemm_fused(
    const bf16_t* __restrict__ Xb,   // [M_][K_]
    const bf16_t* __restrict__ Wb,   // [N2_][K_] (row 2e = Wz[e], 2e+1 = Wh[e])
    const float* __restrict__ bz, const float* __restrict__ bh,
    uint32_t* __restrict__ AB)       // [M_][D_]  packed: lo16 = bf16(a), hi16 = bf16(b)
{
    __shared__ __attribute__((aligned(16))) char lds[131072];

    const int t = threadIdx.x;
    const int wave = t >> 6, lane = t & 63;
    const int wr = wave >> 2, wc = wave & 3;       // 2 x 4 wave grid
    const int fr = lane & 15, ln4 = lane >> 4;
    const int fr7 = fr & 7;
    const int bn0 = blockIdx.x * 256;
    const int bm0 = blockIdx.y * 256;

    // ---- staging geometry (per-thread) ----
    const int l3 = lane >> 3, l7 = lane & 7;
    const int schunk = (l7 ^ l3) * 8;   // inverse-swizzled source chunk, in elements
    const int srow = wave * 8 + l3;     // row within a 64-row j-block

    // ---- read geometry ----
    const int csA[2] = { ((0 + ln4) ^ fr7) * 16, ((4 + ln4) ^ fr7) * 16 }; // kh=0,1
    const int rbaseA = wr * 16384 + fr * 128;  // + mi*2048 + csA[kh]
    const int rbaseB = wc * 8192 + fr * 128;   // + ni*2048 + csA[kh]

    auto stageA = [&](int buf, int h, int u) {
        const bf16_t* g = Xb + (size_t)(bm0 + h * 128 + srow) * K_ + u * 64 + schunk;
        char* l0 = lds + buf * 65536 + h * 16384 + wave * 1024;
        gload_lds16(g, l0);
        gload_lds16(g + (size_t)64 * K_, l0 + 8192);
    };
    auto stageB = [&](int buf, int h, int u) {
        const bf16_t* g = Wb + (size_t)(bn0 + h * 128 + srow) * K_ + u * 64 + schunk;
        char* l0 = lds + buf * 65536 + 32768 + h * 16384 + wave * 1024;
        gload_lds16(g, l0);
        gload_lds16(g + (size_t)64 * K_, l0 + 8192);
    };

#define RD_A(p, mi, kh) (*(const bf16x8*)(lds + (p) * 65536 + rbaseA + (mi) * 2048 + csA[kh]))
#define RD_B(p, ni, kh) (*(const bf16x8*)(lds + (p) * 65536 + 32768 + rbaseB + (ni) * 2048 + csA[kh]))

    f32x4 acc[8][4] = {};
    bf16x8 afr[4][2], bfr[4][2];

    // ---- prologue: tile0 complete + tile1 A-halves; 4 halves (8 loads) in flight ----
    stageA(0, 0, 0); stageA(0, 1, 0); stageB(0, 0, 0); stageB(0, 1, 0);
    stageA(1, 0, 1); stageA(1, 1, 1);
    WAIT_VM(4);   // tile0 landed; tile1 A-halves (4 loads) outstanding
    BAR();

    for (int u = 0; u < NT; ++u) {
        const int p = u & 1;

        // ---- SP1: 12 ds_reads; stage (u+1).B0 -> buf p^1; MFMA Q(m0,n01) ----
#pragma unroll
        for (int mi = 0; mi < 4; ++mi)
#pragma unroll
            for (int kh = 0; kh < 2; ++kh)
                afr[mi][kh] = RD_A(p, mi, kh);
#pragma unroll
        for (int ni = 0; ni < 2; ++ni)
#pragma unroll
            for (int kh = 0; kh < 2; ++kh)
                bfr[ni][kh] = RD_B(p, ni, kh);
        if (u + 1 < NT) stageB(p ^ 1, 0, u + 1);
        BAR();
        __builtin_amdgcn_s_setprio(1);
#pragma unroll
        for (int mi = 0; mi < 4; ++mi)
#pragma unroll
            for (int ni = 0; ni < 2; ++ni)
#pragma unroll
                for (int kh = 0; kh < 2; ++kh)
                    acc[mi][ni] = __builtin_amdgcn_mfma_f32_16x16x32_bf16(
                        afr[mi][kh], bfr[ni][kh], acc[mi][ni], 0, 0, 0);
        __builtin_amdgcn_s_setprio(0);
        BAR();

        // ---- SP2: 4 ds_reads; stage (u+1).B1; MFMA Q(m0,n23) ----
#pragma unroll
        for (int ni = 2; ni < 4; ++ni)
#pragma unroll
            for (int kh = 0; kh < 2; ++kh)
                bfr[ni][kh] = RD_B(p, ni, kh);
        if (u + 1 < NT) stageB(p ^ 1, 1, u + 1);
        BAR();
        __builtin_amdgcn_s_setprio(1);
#pragma unroll
        for (int mi = 0; mi < 4; ++mi)
#pragma unroll
            for (int ni = 2; ni < 4; ++ni)
#pragma unroll
                for (int kh = 0; kh < 2; ++kh)
                    acc[mi][ni] = __builtin_amdgcn_mfma_f32_16x16x32_bf16(
                        afr[mi][kh], bfr[ni][kh], acc[mi][ni], 0, 0, 0);
        __builtin_amdgcn_s_setprio(0);
        BAR();

        // ---- SP3: 8 ds_reads (A mi 4-7); lgkmcnt(0)+BAR certifies buf p fully
        //      read by ALL waves; then stage (u+2).A0 -> buf p; MFMA Q(m1,n01) ----
#pragma unroll
        for (int mi = 0; mi < 4; ++mi)
#pragma unroll
            for (int kh = 0; kh < 2; ++kh)
                afr[mi][kh] = RD_A(p, mi + 4, kh);
        WAIT_LGKM0();
        BAR();
        if (u + 2 < NT) stageA(p, 0, u + 2);
        __builtin_amdgcn_s_setprio(1);
#pragma unroll
        for (int mi = 0; mi < 4; ++mi)
#pragma unroll
            for (int ni = 0; ni < 2; ++ni)
#pragma unroll
                for (int kh = 0; kh < 2; ++kh)
                    acc[mi + 4][ni] = __builtin_amdgcn_mfma_f32_16x16x32_bf16(
                        afr[mi][kh], bfr[ni][kh], acc[mi + 4][ni], 0, 0, 0);
        __builtin_amdgcn_s_setprio(0);
        BAR();

        // ---- SP4: stage (u+2).A1; MFMA Q(m1,n23); counted vmcnt; barrier ----
        if (u + 2 < NT) stageA(p, 1, u + 2);
        __builtin_amdgcn_s_setprio(1);
#pragma unroll
        for (int mi = 0; mi < 4; ++mi)
#pragma unroll
            for (int ni = 2; ni < 4; ++ni)
#pragma unroll
                for (int kh = 0; kh < 2; ++kh)
                    acc[mi + 4][ni] = __builtin_amdgcn_mfma_f32_16x16x32_bf16(
                        afr[mi][kh], bfr[ni][kh], acc[mi + 4][ni], 0, 0, 0);
        __builtin_amdgcn_s_setprio(0);
        if (u < NT - 2)       { WAIT_VM(4); }   // tile u+1 landed; u+2 A-halves in flight
        else if (u == NT - 2) { WAIT_VM(0); }   // drain for the final tile
        BAR();
    }

    // ---- epilogue: even lane (holds z_raw) packs a = 1-z, b = z*h_tilde into one u32 ----
    float bzv[4], bhv[4];
#pragma unroll
    for (int ni = 0; ni < 4; ++ni) {
        int ch = (bn0 + wc * 64 + ni * 16 + fr) >> 1;
        bzv[ni] = bz[ch];
        bhv[ni] = bh[ch];
    }
#pragma unroll
    for (int mi = 0; mi < 8; ++mi) {
#pragma unroll
        for (int ni = 0; ni < 4; ++ni) {
#pragma unroll
            for (int q = 0; q < 4; ++q) {
                float v = acc[mi][ni][q];
                float other = __shfl_xor(v, 1);   // all lanes participate
                if (!(lane & 1)) {
                    int m = bm0 + wr * 128 + mi * 16 + ln4 * 4 + q;
                    int ch = (bn0 + wc * 64 + ni * 16 + fr) >> 1;
                    float z = 1.0f / (1.0f + __expf(-(v + bzv[ni])));
                    bf16_t av = (bf16_t)(1.0f - z);
                    bf16_t bv = (bf16_t)(z * (other + bhv[ni]));
                    uint16_t au, bu;
                    memcpy(&au, &av, 2);
                    memcpy(&bu, &bv, 2);
                    AB[(size_t)m * D_ + ch] = ((uint32_t)bu << 16) | au;
                }
            }
        }
    }
}

// ---------------- scan kernels ----------------

// Pass 1: per-chunk affine composition (A, B): h_out = A*h_in + B
__global__ void scan_chunk_summary(const uint32_t* __restrict__ AB,
                                   float* __restrict__ cA, float* __restrict__ cB) {
    int d = blockIdx.x * blockDim.x + threadIdx.x;
    int c = blockIdx.y, bb = blockIdx.z;
    size_t base = ((size_t)bb * T_ + (size_t)c * CHUNK) * D_ + d;
    float A = 1.0f, Bv = 0.0f;
#pragma unroll 8
    for (int tt = 0; tt < CHUNK; ++tt) {
        uint32_t w = AB[base + (size_t)tt * D_];
        float a = bfbits_to_f(w & 0xffffu);
        float b = bfbits_to_f(w >> 16);
        A *= a;
        Bv = a * Bv + b;
    }
    size_t ci = ((size_t)bb * NC + c) * D_ + d;
    cA[ci] = A;
    cB[ci] = Bv;
}

// Pass 2: apply recurrence within chunk (carry composed inline from chunk summaries)
__global__ void scan_apply(const uint32_t* __restrict__ AB,
                           const float* __restrict__ cA, const float* __restrict__ cB,
                           const float* __restrict__ h_prev, float* __restrict__ out,
                           float* __restrict__ last) {
    int d = blockIdx.x * blockDim.x + threadIdx.x;
    int c = blockIdx.y, bb = blockIdx.z;

    // inline carry: h = (chunk_{c-1} ∘ ... ∘ chunk_0)(h_prev)
    float h = h_prev[(size_t)bb * D_ + d];
    size_t cbase = (size_t)bb * NC * D_ + d;
#pragma unroll 4
    for (int cc = 0; cc < c; ++cc)
        h = cA[cbase + (size_t)cc * D_] * h + cB[cbase + (size_t)cc * D_];

    size_t base = ((size_t)bb * T_ + (size_t)c * CHUNK) * D_ + d;
#pragma unroll 8
    for (int tt = 0; tt < CHUNK; ++tt) {
        uint32_t w = AB[base + (size_t)tt * D_];
        float a = bfbits_to_f(w & 0xffffu);
        float b = bfbits_to_f(w >> 16);
        h = a * h + b;
        out[base + (size_t)tt * D_] = h;
    }
    if (c == NC - 1) last[(size_t)bb * D_ + d] = h;
}

// ---------------- launch ----------------

extern "C" void kernel_launch(void* const* d_in, const int* in_sizes, int n_in,
                              void* d_out, int out_size, void* d_ws, size_t ws_size,
                              hipStream_t stream) {
    const float* x      = (const float*)d_in[0];
    const float* h_prev = (const float*)d_in[1];
    const float* Wz     = (const float*)d_in[2];
    const float* bz     = (const float*)d_in[3];
    const float* Wh     = (const float*)d_in[4];
    const float* bh     = (const float*)d_in[5];

    float* out  = (float*)d_out;
    float* last = out + (size_t)M_ * D_;

    char* ws = (char*)d_ws;
    bf16_t*   Xb = (bf16_t*)ws;                                  // M_*K_ bf16 (64 MB)
    bf16_t*   Wb = (bf16_t*)(ws + (size_t)M_ * K_ * 2);          // N2_*K_ bf16 (16 MB)
    uint32_t* AB = (uint32_t*)((char*)Wb + (size_t)N2_ * K_ * 2);// M_*D_ u32 (128 MB)
    float*    cA = (float*)((char*)AB + (size_t)M_ * D_ * 4);    // 2 MB
    float*    cB = cA + (size_t)B_ * NC * D_;                    // 2 MB

    {
        int n4 = M_ * K_ / 4;
        conv_x_kernel<<<(n4 + 255) / 256, 256, 0, stream>>>((const float4*)x, (bf16x4*)Xb, n4);
    }
    {
        int n4 = D_ * D_ / 4;
        conv_w_kernel<<<(n4 + 255) / 256, 256, 0, stream>>>((const float4*)Wz, (const float4*)Wh,
                                                            (bf16x4*)Wb, n4, D_ / 4);
    }
    gemm_fused<<<dim3(N2_ / 256, M_ / 256), 512, 0, stream>>>(Xb, Wb, bz, bh, AB);
    scan_chunk_summary<<<dim3(D_ / 256, NC, B_), 256, 0, stream>>>(AB, cA, cB);
    scan_apply<<<dim3(D_ / 256, NC, B_), 256, 0, stream>>>(AB, cA, cB, h_prev, out, last);
}

// Round 14
// 548.408 us; speedup vs baseline: 1.1159x; 1.1159x over previous
//
#include <hip/hip_runtime.h>
#include <hip/hip_bf16.h>
#include <cstdint>
#include <cstring>

typedef __bf16 bf16_t;
typedef __attribute__((ext_vector_type(8))) __bf16 bf16x8;
typedef __attribute__((ext_vector_type(4))) __bf16 bf16x4;
typedef __attribute__((ext_vector_type(4))) float f32x4;

#define B_ 8
#define T_ 2048
#define D_ 2048
#define M_ (B_ * T_)   // 16384
#define N2_ (2 * D_)   // 4096 (interleaved z/h columns)
#define K_ D_          // 2048
#define NT (K_ / 64)   // 32 K-tiles of BK=64

#define NC 32
#define CHUNK (T_ / NC)  // 64

#define BAR() __builtin_amdgcn_s_barrier()
#define WAIT_LGKM0() asm volatile("s_waitcnt lgkmcnt(0)" ::: "memory")
#define WAIT_VM(n) asm volatile("s_waitcnt vmcnt(" #n ")" ::: "memory")

__device__ __forceinline__ float bfbits_to_f(uint32_t u16) {
    uint32_t u = u16 << 16;
    float f;
    memcpy(&f, &u, 4);
    return f;
}

// ---------------- conversion kernels ----------------

__global__ void conv_x_kernel(const float4* __restrict__ in, bf16x4* __restrict__ out, int n4) {
    int i = blockIdx.x * blockDim.x + threadIdx.x;
    if (i >= n4) return;
    float4 v = in[i];
    bf16x4 o = { (bf16_t)v.x, (bf16_t)v.y, (bf16_t)v.z, (bf16_t)v.w };
    out[i] = o;
}

// Pack Wz/Wh interleaved by row: Wb[2e] = Wz[e], Wb[2e+1] = Wh[e]
__global__ void conv_w_kernel(const float4* __restrict__ Wz, const float4* __restrict__ Wh,
                              bf16x4* __restrict__ Wb, int n4, int d4) {
    int i = blockIdx.x * blockDim.x + threadIdx.x;
    if (i >= n4) return;
    int row = i / d4;
    int c = i - row * d4;
    float4 vz = Wz[i];
    float4 vh = Wh[i];
    bf16x4 oz = { (bf16_t)vz.x, (bf16_t)vz.y, (bf16_t)vz.z, (bf16_t)vz.w };
    bf16x4 oh = { (bf16_t)vh.x, (bf16_t)vh.y, (bf16_t)vh.z, (bf16_t)vh.w };
    Wb[(size_t)(2 * row) * d4 + c] = oz;
    Wb[(size_t)(2 * row + 1) * d4 + c] = oh;
}

// ---------------- GEMM (256x256, BK=64, 8-phase, swizzled LDS) ----------------

__device__ __forceinline__ void gload_lds16(const bf16_t* g, char* l) {
    __builtin_amdgcn_global_load_lds(
        (__attribute__((address_space(1))) void*)(g),
        (__attribute__((address_space(3))) void*)(l), 16, 0, 0);
}

// LDS map (per buffer p in {0,1}):  A at p*65536, B at p*65536+32768.
// Logical tile [256 rows][64 k] bf16, row stride 128B; within a row, 16B chunk
// c stored at chunk slot c ^ (row & 7)  (T2 XOR swizzle, bank-conflict-free).
// global_load_lds writes linearly; the global SOURCE address is pre-inverse-swizzled.

__global__ __launch_bounds__(512, 2) void gemm_fused(
    const bf16_t* __restrict__ Xb,   // [M_][K_]
    const bf16_t* __restrict__ Wb,   // [N2_][K_] (row 2e = Wz[e], 2e+1 = Wh[e])
    const float* __restrict__ bz, const float* __restrict__ bh,
    uint32_t* __restrict__ AB)       // [M_][D_]  packed: lo16 = bf16(a), hi16 = bf16(b)
{
    __shared__ __attribute__((aligned(16))) char lds[131072];

    const int t = threadIdx.x;
    const int wave = t >> 6, lane = t & 63;
    const int wr = wave >> 2, wc = wave & 3;       // 2 x 4 wave grid
    const int fr = lane & 15, ln4 = lane >> 4;
    const int fr7 = fr & 7;
    const int bn0 = blockIdx.x * 256;
    const int bm0 = blockIdx.y * 256;

    // ---- staging geometry (per-thread) ----
    const int l3 = lane >> 3, l7 = lane & 7;
    const int schunk = (l7 ^ l3) * 8;   // inverse-swizzled source chunk, in elements
    const int srow = wave * 8 + l3;     // row within a 64-row j-block

    // ---- read geometry ----
    const int csA[2] = { ((0 + ln4) ^ fr7) * 16, ((4 + ln4) ^ fr7) * 16 }; // kh=0,1
    const int rbaseA = wr * 16384 + fr * 128;  // + mi*2048 + csA[kh]
    const int rbaseB = wc * 8192 + fr * 128;   // + ni*2048 + csA[kh]

    auto stageA = [&](int buf, int h, int u) {
        const bf16_t* g = Xb + (size_t)(bm0 + h * 128 + srow) * K_ + u * 64 + schunk;
        char* l0 = lds + buf * 65536 + h * 16384 + wave * 1024;
        gload_lds16(g, l0);
        gload_lds16(g + (size_t)64 * K_, l0 + 8192);
    };
    auto stageB = [&](int buf, int h, int u) {
        const bf16_t* g = Wb + (size_t)(bn0 + h * 128 + srow) * K_ + u * 64 + schunk;
        char* l0 = lds + buf * 65536 + 32768 + h * 16384 + wave * 1024;
        gload_lds16(g, l0);
        gload_lds16(g + (size_t)64 * K_, l0 + 8192);
    };

#define RD_A(p, mi, kh) (*(const bf16x8*)(lds + (p) * 65536 + rbaseA + (mi) * 2048 + csA[kh]))
#define RD_B(p, ni, kh) (*(const bf16x8*)(lds + (p) * 65536 + 32768 + rbaseB + (ni) * 2048 + csA[kh]))

    f32x4 acc[8][4] = {};
    bf16x8 afr[4][2], bfr[4][2];

    // ---- prologue: tile0 complete + tile1 A-halves; 4 halves (8 loads) in flight ----
    stageA(0, 0, 0); stageA(0, 1, 0); stageB(0, 0, 0); stageB(0, 1, 0);
    stageA(1, 0, 1); stageA(1, 1, 1);
    WAIT_VM(4);   // tile0 landed; tile1 A-halves (4 loads) outstanding
    BAR();

    for (int u = 0; u < NT; ++u) {
        const int p = u & 1;

        // ---- SP1: 12 ds_reads; stage (u+1).B0 -> buf p^1; MFMA Q(m0,n01) ----
#pragma unroll
        for (int mi = 0; mi < 4; ++mi)
#pragma unroll
            for (int kh = 0; kh < 2; ++kh)
                afr[mi][kh] = RD_A(p, mi, kh);
#pragma unroll
        for (int ni = 0; ni < 2; ++ni)
#pragma unroll
            for (int kh = 0; kh < 2; ++kh)
                bfr[ni][kh] = RD_B(p, ni, kh);
        if (u + 1 < NT) stageB(p ^ 1, 0, u + 1);
        BAR();
        __builtin_amdgcn_s_setprio(1);
#pragma unroll
        for (int mi = 0; mi < 4; ++mi)
#pragma unroll
            for (int ni = 0; ni < 2; ++ni)
#pragma unroll
                for (int kh = 0; kh < 2; ++kh)
                    acc[mi][ni] = __builtin_amdgcn_mfma_f32_16x16x32_bf16(
                        afr[mi][kh], bfr[ni][kh], acc[mi][ni], 0, 0, 0);
        __builtin_amdgcn_s_setprio(0);
        BAR();

        // ---- SP2: 4 ds_reads; stage (u+1).B1; MFMA Q(m0,n23) ----
#pragma unroll
        for (int ni = 2; ni < 4; ++ni)
#pragma unroll
            for (int kh = 0; kh < 2; ++kh)
                bfr[ni][kh] = RD_B(p, ni, kh);
        if (u + 1 < NT) stageB(p ^ 1, 1, u + 1);
        BAR();
        __builtin_amdgcn_s_setprio(1);
#pragma unroll
        for (int mi = 0; mi < 4; ++mi)
#pragma unroll
            for (int ni = 2; ni < 4; ++ni)
#pragma unroll
                for (int kh = 0; kh < 2; ++kh)
                    acc[mi][ni] = __builtin_amdgcn_mfma_f32_16x16x32_bf16(
                        afr[mi][kh], bfr[ni][kh], acc[mi][ni], 0, 0, 0);
        __builtin_amdgcn_s_setprio(0);
        BAR();

        // ---- SP3: 8 ds_reads (A mi 4-7); lgkmcnt(0)+BAR certifies buf p fully
        //      read by ALL waves; then stage (u+2).A0 -> buf p; MFMA Q(m1,n01) ----
#pragma unroll
        for (int mi = 0; mi < 4; ++mi)
#pragma unroll
            for (int kh = 0; kh < 2; ++kh)
                afr[mi][kh] = RD_A(p, mi + 4, kh);
        WAIT_LGKM0();
        BAR();
        if (u + 2 < NT) stageA(p, 0, u + 2);
        __builtin_amdgcn_s_setprio(1);
#pragma unroll
        for (int mi = 0; mi < 4; ++mi)
#pragma unroll
            for (int ni = 0; ni < 2; ++ni)
#pragma unroll
                for (int kh = 0; kh < 2; ++kh)
                    acc[mi + 4][ni] = __builtin_amdgcn_mfma_f32_16x16x32_bf16(
                        afr[mi][kh], bfr[ni][kh], acc[mi + 4][ni], 0, 0, 0);
        __builtin_amdgcn_s_setprio(0);
        BAR();

        // ---- SP4: stage (u+2).A1; MFMA Q(m1,n23); counted vmcnt; barrier ----
        if (u + 2 < NT) stageA(p, 1, u + 2);
        __builtin_amdgcn_s_setprio(1);
#pragma unroll
        for (int mi = 0; mi < 4; ++mi)
#pragma unroll
            for (int ni = 2; ni < 4; ++ni)
#pragma unroll
                for (int kh = 0; kh < 2; ++kh)
                    acc[mi + 4][ni] = __builtin_amdgcn_mfma_f32_16x16x32_bf16(
                        afr[mi][kh], bfr[ni][kh], acc[mi + 4][ni], 0, 0, 0);
        __builtin_amdgcn_s_setprio(0);
        if (u < NT - 2)       { WAIT_VM(4); }   // tile u+1 landed; u+2 A-halves in flight
        else if (u == NT - 2) { WAIT_VM(0); }   // drain for the final tile
        BAR();
    }

    // ---- epilogue: all 64 lanes pack a = 1-z, b = z*h_tilde into one u32 ----
    // Lane pair (2j, 2j+1) holds (z_raw, h_raw) for the same (m-range, ch).
    // After shfl_xor(1) BOTH lanes have both values, so split the q-quad:
    // even lane packs tuples q in {0,1}, odd lane packs q in {2,3}.
    const int odd = lane & 1;
    float bzv[4], bhv[4];
#pragma unroll
    for (int ni = 0; ni < 4; ++ni) {
        int ch = (bn0 + wc * 64 + ni * 16 + fr) >> 1;
        bzv[ni] = bz[ch];
        bhv[ni] = bh[ch];
    }
#pragma unroll
    for (int mi = 0; mi < 8; ++mi) {
#pragma unroll
        for (int ni = 0; ni < 4; ++ni) {
            int ch = (bn0 + wc * 64 + ni * 16 + fr) >> 1;
            int mb = bm0 + wr * 128 + mi * 16 + ln4 * 4;
#pragma unroll
            for (int qq = 0; qq < 2; ++qq) {
                float ve = acc[mi][ni][qq];       // tuple q = qq     (z on even / h on odd)
                float vo = acc[mi][ni][qq + 2];   // tuple q = qq + 2
                float pe = __shfl_xor(ve, 1);
                float po = __shfl_xor(vo, 1);
                float zraw = odd ? po : ve;
                float hraw = odd ? vo : pe;
                int m = mb + (odd ? qq + 2 : qq);
                float z = 1.0f / (1.0f + __expf(-(zraw + bzv[ni])));
                bf16_t av = (bf16_t)(1.0f - z);
                bf16_t bv = (bf16_t)(z * (hraw + bhv[ni]));
                uint16_t au, bu;
                memcpy(&au, &av, 2);
                memcpy(&bu, &bv, 2);
                AB[(size_t)m * D_ + ch] = ((uint32_t)bu << 16) | au;
            }
        }
    }
}

// ---------------- scan kernels ----------------

// Pass 1: per-chunk affine composition (A, B): h_out = A*h_in + B
__global__ void scan_chunk_summary(const uint32_t* __restrict__ AB,
                                   float* __restrict__ cA, float* __restrict__ cB) {
    int d = blockIdx.x * blockDim.x + threadIdx.x;
    int c = blockIdx.y, bb = blockIdx.z;
    size_t base = ((size_t)bb * T_ + (size_t)c * CHUNK) * D_ + d;
    float A = 1.0f, Bv = 0.0f;
#pragma unroll 8
    for (int tt = 0; tt < CHUNK; ++tt) {
        uint32_t w = AB[base + (size_t)tt * D_];
        float a = bfbits_to_f(w & 0xffffu);
        float b = bfbits_to_f(w >> 16);
        A *= a;
        Bv = a * Bv + b;
    }
    size_t ci = ((size_t)bb * NC + c) * D_ + d;
    cA[ci] = A;
    cB[ci] = Bv;
}

// Pass 2: apply recurrence within chunk (carry composed inline from chunk summaries)
__global__ void scan_apply(const uint32_t* __restrict__ AB,
                           const float* __restrict__ cA, const float* __restrict__ cB,
                           const float* __restrict__ h_prev, float* __restrict__ out,
                           float* __restrict__ last) {
    int d = blockIdx.x * blockDim.x + threadIdx.x;
    int c = blockIdx.y, bb = blockIdx.z;

    // inline carry: h = (chunk_{c-1} ∘ ... ∘ chunk_0)(h_prev)
    float h = h_prev[(size_t)bb * D_ + d];
    size_t cbase = (size_t)bb * NC * D_ + d;
#pragma unroll 4
    for (int cc = 0; cc < c; ++cc)
        h = cA[cbase + (size_t)cc * D_] * h + cB[cbase + (size_t)cc * D_];

    size_t base = ((size_t)bb * T_ + (size_t)c * CHUNK) * D_ + d;
#pragma unroll 8
    for (int tt = 0; tt < CHUNK; ++tt) {
        uint32_t w = AB[base + (size_t)tt * D_];
        float a = bfbits_to_f(w & 0xffffu);
        float b = bfbits_to_f(w >> 16);
        h = a * h + b;
        out[base + (size_t)tt * D_] = h;
    }
    if (c == NC - 1) last[(size_t)bb * D_ + d] = h;
}

// ---------------- launch ----------------

extern "C" void kernel_launch(void* const* d_in, const int* in_sizes, int n_in,
                              void* d_out, int out_size, void* d_ws, size_t ws_size,
                              hipStream_t stream) {
    const float* x      = (const float*)d_in[0];
    const float* h_prev = (const float*)d_in[1];
    const float* Wz     = (const float*)d_in[2];
    const float* bz     = (const float*)d_in[3];
    const float* Wh     = (const float*)d_in[4];
    const float* bh     = (const float*)d_in[5];

    float* out  = (float*)d_out;
    float* last = out + (size_t)M_ * D_;

    char* ws = (char*)d_ws;
    bf16_t*   Xb = (bf16_t*)ws;                                  // M_*K_ bf16 (64 MB)
    bf16_t*   Wb = (bf16_t*)(ws + (size_t)M_ * K_ * 2);          // N2_*K_ bf16 (16 MB)
    uint32_t* AB = (uint32_t*)((char*)Wb + (size_t)N2_ * K_ * 2);// M_*D_ u32 (128 MB)
    float*    cA = (float*)((char*)AB + (size_t)M_ * D_ * 4);    // 2 MB
    float*    cB = cA + (size_t)B_ * NC * D_;                    // 2 MB

    {
        int n4 = M_ * K_ / 4;
        conv_x_kernel<<<(n4 + 255) / 256, 256, 0, stream>>>((const float4*)x, (bf16x4*)Xb, n4);
    }
    {
        int n4 = D_ * D_ / 4;
        conv_w_kernel<<<(n4 + 255) / 256, 256, 0, stream>>>((const float4*)Wz, (const float4*)Wh,
                                                            (bf16x4*)Wb, n4, D_ / 4);
    }
    gemm_fused<<<dim3(N2_ / 256, M_ / 256), 512, 0, stream>>>(Xb, Wb, bz, bh, AB);
    scan_chunk_summary<<<dim3(D_ / 256, NC, B_), 256, 0, stream>>>(AB, cA, cB);
    scan_apply<<<dim3(D_ / 256, NC, B_), 256, 0, stream>>>(AB, cA, cB, h_prev, out, last);
}